// Round 1
// baseline (786.976 us; speedup 1.0000x reference)
//
#include <hip/hip_runtime.h>
#include <hip/hip_bf16.h>
#include <math.h>

typedef __attribute__((ext_vector_type(8))) short bf16x8;
typedef __attribute__((ext_vector_type(4))) float f32x4;
typedef unsigned short u16;

#define NHEAD 12

__device__ __forceinline__ u16 f2bf(float f) {
  unsigned int u = __builtin_bit_cast(unsigned int, f);
  return (u16)((u + 0x7fffu + ((u >> 16) & 1u)) >> 16);
}

__device__ __forceinline__ void gload16(const void* g, void* l) {
  __builtin_amdgcn_global_load_lds(
      (const __attribute__((address_space(1))) void*)g,
      (__attribute__((address_space(3))) void*)l, 16, 0, 0);
}

// ---------------- weight fp32 -> bf16 ----------------
__global__ void cvt_w(const float* __restrict__ s, u16* __restrict__ d, int n) {
  int i = blockIdx.x * 256 + threadIdx.x;
  if (i < n) d[i] = f2bf(s[i]);
}

// ---------------- relative-position bias table [12][64][64] ----------------
__global__ void build_bias(const float* __restrict__ rpb, float* __restrict__ bt) {
  int i = blockIdx.x * 256 + threadIdx.x;  // 12*64*64 = 49152
  if (i >= NHEAD * 4096) return;
  int h = i >> 12;
  int q = (i >> 6) & 63;
  int k = i & 63;
  int qi = q >> 3, qj = q & 7, ki = k >> 3, kj = k & 7;
  int idx = (qi - ki + 7) * 15 + (qj - kj + 7);
  bt[i] = rpb[idx * NHEAD + h];
}

// ---------------- LayerNorm: fp32 in -> bf16 out, C=384, 1 wave/row ----------------
__global__ __launch_bounds__(256) void ln_k(const float* __restrict__ x,
                                            const float* __restrict__ g,
                                            const float* __restrict__ b,
                                            u16* __restrict__ out) {
  int row = (blockIdx.x << 2) + (threadIdx.x >> 6);
  int lane = threadIdx.x & 63;
  const float* xr = x + (size_t)row * 384;
  float v[6];
  float s = 0.f;
#pragma unroll
  for (int i = 0; i < 6; ++i) { v[i] = xr[lane + (i << 6)]; s += v[i]; }
#pragma unroll
  for (int o = 32; o; o >>= 1) s += __shfl_xor(s, o, 64);
  float mu = s * (1.f / 384.f);
  float vs = 0.f;
#pragma unroll
  for (int i = 0; i < 6; ++i) { float d0 = v[i] - mu; vs += d0 * d0; }
#pragma unroll
  for (int o = 32; o; o >>= 1) vs += __shfl_xor(vs, o, 64);
  float rs = rsqrtf(vs * (1.f / 384.f) + 1e-5f);
  u16* orow = out + (size_t)row * 384;
#pragma unroll
  for (int i = 0; i < 6; ++i) {
    int c = lane + (i << 6);
    orow[c] = f2bf((v[i] - mu) * rs * g[c] + b[c]);
  }
}

// ---------------- GEMM: out[M,N] = A[M,K](bf16) @ W[N,K]^T(bf16) + bias, epilogues ----------------
// EP 0: +bias -> bf16           (QKV)
// EP 1: +bias +res -> fp32      (proj + residual x)
// EP 2: +bias, gelu -> bf16     (FC1)
// EP 3: +bias +res -> fp32      (FC2 + residual x1)
template <int EP>
__global__ __launch_bounds__(256) void gemm_k(const u16* __restrict__ A,
                                              const u16* __restrict__ W,
                                              const float* __restrict__ bias,
                                              const float* __restrict__ res,
                                              void* __restrict__ outp, int N, int K) {
  __shared__ u16 As[128 * 64];
  __shared__ u16 Bs[128 * 64];
  const int tid = threadIdx.x;
  const int wave = tid >> 6, lane = tid & 63;
  const int rowBase = blockIdx.x << 7;
  const int colBase = blockIdx.y << 7;
  const int wr = (wave >> 1) << 6;
  const int wc = (wave & 1) << 6;
  f32x4 acc[4][4] = {};
  const int nK = K >> 6;
  const int r0 = tid >> 3;        // 0..31
  const int kb = (tid & 7) << 3;  // 0..56 (elements)
  for (int kt = 0; kt < nK; ++kt) {
    const int k0 = kt << 6;
#pragma unroll
    for (int c = 0; c < 4; ++c) {
      int r = (c << 5) + r0;
      gload16(A + (size_t)(rowBase + r) * K + (k0 + kb), &As[(r << 6) + kb]);
    }
#pragma unroll
    for (int c = 0; c < 4; ++c) {
      int r = (c << 5) + r0;
      gload16(W + (size_t)(colBase + r) * K + (k0 + kb), &Bs[(r << 6) + kb]);
    }
    asm volatile("s_waitcnt vmcnt(0)" ::: "memory");
    __syncthreads();
#pragma unroll
    for (int kk = 0; kk < 2; ++kk) {
      bf16x8 af[4], bfr[4];
#pragma unroll
      for (int m = 0; m < 4; ++m)
        af[m] = *(const bf16x8*)&As[(wr + (m << 4) + (lane & 15)) * 64 + (kk << 5) + ((lane >> 4) << 3)];
#pragma unroll
      for (int n = 0; n < 4; ++n)
        bfr[n] = *(const bf16x8*)&Bs[(wc + (n << 4) + (lane & 15)) * 64 + (kk << 5) + ((lane >> 4) << 3)];
#pragma unroll
      for (int m = 0; m < 4; ++m)
#pragma unroll
        for (int n = 0; n < 4; ++n)
          acc[m][n] = __builtin_amdgcn_mfma_f32_16x16x32_bf16(af[m], bfr[n], acc[m][n], 0, 0, 0);
    }
    __syncthreads();
  }
#pragma unroll
  for (int m = 0; m < 4; ++m) {
#pragma unroll
    for (int n = 0; n < 4; ++n) {
      const int col = colBase + wc + (n << 4) + (lane & 15);
      const int row0 = rowBase + wr + (m << 4) + ((lane >> 4) << 2);
      const float bv = bias[col];
#pragma unroll
      for (int j = 0; j < 4; ++j) {
        const size_t row = (size_t)(row0 + j);
        float y = acc[m][n][j] + bv;
        if (EP == 0) {
          ((u16*)outp)[row * N + col] = f2bf(y);
        } else if (EP == 1) {
          ((float*)outp)[row * N + col] = y + res[row * N + col];
        } else if (EP == 2) {
          y = 0.5f * y * (1.f + erff(y * 0.70710678118f));
          ((u16*)outp)[row * N + col] = f2bf(y);
        } else {
          ((float*)outp)[row * N + col] = y + res[row * N + col];
        }
      }
    }
  }
}

// ---------------- window attention: one block per (window, head) ----------------
__global__ __launch_bounds__(256) void attn_k(const u16* __restrict__ qkv,
                                              const float* __restrict__ bias_tab,
                                              u16* __restrict__ o) {
  const int blk = blockIdx.x;
  const int w = blk / NHEAD;
  const int h = blk - w * NHEAD;
  const int tid = threadIdx.x, wave = tid >> 6, lane = tid & 63;
  __shared__ u16 q_s[64 * 32];
  __shared__ u16 k_s[64 * 32];
  __shared__ u16 vt_s[32 * 64];      // transposed [d][key]
  __shared__ u16 p_s[4][16 * 72];    // per-wave P, padded stride 72
  const int b = w >> 6;
  const int wim = w & 63;
  const int wr0 = (wim >> 3) << 3, wc0 = (wim & 7) << 3;
  {
    const int r = tid >> 2, d0 = (tid & 3) << 3;
    const int pr = r >> 3, pc = r & 7;
    const int orow = (wr0 + pr + 4) & 63, ocol = (wc0 + pc + 4) & 63;
    const size_t t = ((size_t)b << 12) + (orow << 6) + ocol;
    const u16* base = qkv + t * 1152 + h * 32 + d0;
    *(uint4*)&q_s[r * 32 + d0] = *(const uint4*)(base);
    *(uint4*)&k_s[r * 32 + d0] = *(const uint4*)(base + 384);
    u16 vv[8];
    *(uint4*)vv = *(const uint4*)(base + 768);
#pragma unroll
    for (int j = 0; j < 8; ++j) vt_s[(d0 + j) * 64 + r] = vv[j];
  }
  __syncthreads();
  const int cIdx = lane & 15, rgrp = lane >> 4;
  const f32x4 zz = {0.f, 0.f, 0.f, 0.f};
  bf16x8 qa = *(const bf16x8*)&q_s[((wave << 4) + cIdx) * 32 + (rgrp << 3)];
  f32x4 s_acc[4];
#pragma unroll
  for (int n = 0; n < 4; ++n) {
    bf16x8 kb = *(const bf16x8*)&k_s[((n << 4) + cIdx) * 32 + (rgrp << 3)];
    s_acc[n] = __builtin_amdgcn_mfma_f32_16x16x32_bf16(qa, kb, zz, 0, 0, 0);
  }
  const float scale = 0.1767766952966369f;  // 1/sqrt(32)
  float mrow[4] = {-1e30f, -1e30f, -1e30f, -1e30f};
  const float* bt = bias_tab + h * 4096 + ((wave << 4) + (rgrp << 2)) * 64 + cIdx;
#pragma unroll
  for (int n = 0; n < 4; ++n)
#pragma unroll
    for (int j = 0; j < 4; ++j) {
      float val = s_acc[n][j] * scale + bt[j * 64 + (n << 4)];
      s_acc[n][j] = val;
      mrow[j] = fmaxf(mrow[j], val);
    }
#pragma unroll
  for (int j = 0; j < 4; ++j)
#pragma unroll
    for (int o2 = 1; o2 < 16; o2 <<= 1) mrow[j] = fmaxf(mrow[j], __shfl_xor(mrow[j], o2, 64));
  float srow[4] = {0.f, 0.f, 0.f, 0.f};
#pragma unroll
  for (int n = 0; n < 4; ++n)
#pragma unroll
    for (int j = 0; j < 4; ++j) {
      float e = __expf(s_acc[n][j] - mrow[j]);
      s_acc[n][j] = e;
      srow[j] += e;
    }
#pragma unroll
  for (int j = 0; j < 4; ++j)
#pragma unroll
    for (int o2 = 1; o2 < 16; o2 <<= 1) srow[j] += __shfl_xor(srow[j], o2, 64);
  float rinv[4];
#pragma unroll
  for (int j = 0; j < 4; ++j) rinv[j] = 1.f / srow[j];
  u16* pw = p_s[wave];
#pragma unroll
  for (int n = 0; n < 4; ++n)
#pragma unroll
    for (int j = 0; j < 4; ++j)
      pw[((rgrp << 2) + j) * 72 + (n << 4) + cIdx] = f2bf(s_acc[n][j] * rinv[j]);
  f32x4 o_acc[2] = {};
#pragma unroll
  for (int kk = 0; kk < 2; ++kk) {
    bf16x8 pa = *(const bf16x8*)&pw[cIdx * 72 + (kk << 5) + (rgrp << 3)];
#pragma unroll
    for (int c2 = 0; c2 < 2; ++c2) {
      bf16x8 vb = *(const bf16x8*)&vt_s[((c2 << 4) + cIdx) * 64 + (kk << 5) + (rgrp << 3)];
      o_acc[c2] = __builtin_amdgcn_mfma_f32_16x16x32_bf16(pa, vb, o_acc[c2], 0, 0, 0);
    }
  }
#pragma unroll
  for (int c2 = 0; c2 < 2; ++c2)
#pragma unroll
    for (int j = 0; j < 4; ++j) {
      const int p = (wave << 4) + (rgrp << 2) + j;
      const int pr = p >> 3, pc = p & 7;
      const int orow = (wr0 + pr + 4) & 63, ocol = (wc0 + pc + 4) & 63;
      const size_t t = ((size_t)b << 12) + (orow << 6) + ocol;
      o[t * 384 + h * 32 + (c2 << 4) + cIdx] = f2bf(o_acc[c2][j]);
    }
}

extern "C" void kernel_launch(void* const* d_in, const int* in_sizes, int n_in,
                              void* d_out, int out_size, void* d_ws, size_t ws_size,
                              hipStream_t stream) {
  const float* x = (const float*)d_in[0];
  const float* n1g = (const float*)d_in[1];
  const float* n1b = (const float*)d_in[2];
  const float* qkv_w = (const float*)d_in[3];
  const float* qkv_b = (const float*)d_in[4];
  const float* proj_w = (const float*)d_in[5];
  const float* proj_b = (const float*)d_in[6];
  const float* rpb = (const float*)d_in[7];
  const float* n2g = (const float*)d_in[8];
  const float* n2b = (const float*)d_in[9];
  const float* fc1_w = (const float*)d_in[10];
  const float* fc1_b = (const float*)d_in[11];
  const float* fc2_w = (const float*)d_in[12];
  const float* fc2_b = (const float*)d_in[13];

  char* ws = (char*)d_ws;
  u16* wqkv = (u16*)(ws + 0);                   // 884736 B
  u16* wproj = (u16*)(ws + 884736);             // 294912 B
  u16* wfc1 = (u16*)(ws + 1179648);             // 1179648 B
  u16* wfc2 = (u16*)(ws + 2359296);             // 1179648 B
  float* bias_tab = (float*)(ws + 3538944);     // 196608 B
  u16* qkv = (u16*)(ws + 3735552);              // region A: 201326592 B (qkv then m1)
  u16* m1 = qkv;
  u16* hbuf = (u16*)(ws + 205062144);           // region B: 50331648 B (h -> o -> h2)
  u16* obuf = hbuf;
  float* x1 = (float*)d_out;                    // x1 lives in d_out

  cvt_w<<<(442368 + 255) / 256, 256, 0, stream>>>(qkv_w, wqkv, 442368);
  cvt_w<<<(147456 + 255) / 256, 256, 0, stream>>>(proj_w, wproj, 147456);
  cvt_w<<<(589824 + 255) / 256, 256, 0, stream>>>(fc1_w, wfc1, 589824);
  cvt_w<<<(589824 + 255) / 256, 256, 0, stream>>>(fc2_w, wfc2, 589824);
  build_bias<<<192, 256, 0, stream>>>(rpb, bias_tab);

  ln_k<<<16384, 256, 0, stream>>>(x, n1g, n1b, hbuf);
  gemm_k<0><<<dim3(512, 9), 256, 0, stream>>>(hbuf, wqkv, qkv_b, nullptr, qkv, 1152, 384);
  attn_k<<<12288, 256, 0, stream>>>(qkv, bias_tab, obuf);
  gemm_k<1><<<dim3(512, 3), 256, 0, stream>>>(obuf, wproj, proj_b, x, x1, 384, 384);
  ln_k<<<16384, 256, 0, stream>>>(x1, n2g, n2b, hbuf);
  gemm_k<2><<<dim3(512, 12), 256, 0, stream>>>(hbuf, wfc1, fc1_b, nullptr, m1, 1536, 384);
  gemm_k<3><<<dim3(512, 3), 256, 0, stream>>>(m1, wfc2, fc2_b, x1, (float*)d_out, 384, 1536);
}

// Round 2
// 707.123 us; speedup vs baseline: 1.1129x; 1.1129x over previous
//
#include <hip/hip_runtime.h>
#include <hip/hip_bf16.h>
#include <math.h>

typedef __attribute__((ext_vector_type(8))) short bf16x8;
typedef __attribute__((ext_vector_type(4))) float f32x4;
typedef unsigned short u16;

#define NHEAD 12

__device__ __forceinline__ u16 f2bf(float f) {
  unsigned int u = __builtin_bit_cast(unsigned int, f);
  return (u16)((u + 0x7fffu + ((u >> 16) & 1u)) >> 16);
}

__device__ __forceinline__ void gload16(const void* g, void* l) {
  __builtin_amdgcn_global_load_lds(
      (const __attribute__((address_space(1))) void*)g,
      (__attribute__((address_space(3))) void*)l, 16, 0, 0);
}

// ---------------- weight fp32 -> bf16 ----------------
__global__ void cvt_w(const float* __restrict__ s, u16* __restrict__ d, int n) {
  int i = blockIdx.x * 256 + threadIdx.x;
  if (i < n) d[i] = f2bf(s[i]);
}

// ---------------- relative-position bias table [12][64][64] ----------------
__global__ void build_bias(const float* __restrict__ rpb, float* __restrict__ bt) {
  int i = blockIdx.x * 256 + threadIdx.x;  // 12*64*64 = 49152
  if (i >= NHEAD * 4096) return;
  int h = i >> 12;
  int q = (i >> 6) & 63;
  int k = i & 63;
  int qi = q >> 3, qj = q & 7, ki = k >> 3, kj = k & 7;
  int idx = (qi - ki + 7) * 15 + (qj - kj + 7);
  bt[i] = rpb[idx * NHEAD + h];
}

// ---------------- LayerNorm: fp32 in -> bf16 out, C=384, 1 wave/row ----------------
__global__ __launch_bounds__(256) void ln_k(const float* __restrict__ x,
                                            const float* __restrict__ g,
                                            const float* __restrict__ b,
                                            u16* __restrict__ out) {
  int row = (blockIdx.x << 2) + (threadIdx.x >> 6);
  int lane = threadIdx.x & 63;
  const float* xr = x + (size_t)row * 384;
  float v[6];
  float s = 0.f;
#pragma unroll
  for (int i = 0; i < 6; ++i) { v[i] = xr[lane + (i << 6)]; s += v[i]; }
#pragma unroll
  for (int o = 32; o; o >>= 1) s += __shfl_xor(s, o, 64);
  float mu = s * (1.f / 384.f);
  float vs = 0.f;
#pragma unroll
  for (int i = 0; i < 6; ++i) { float d0 = v[i] - mu; vs += d0 * d0; }
#pragma unroll
  for (int o = 32; o; o >>= 1) vs += __shfl_xor(vs, o, 64);
  float rs = rsqrtf(vs * (1.f / 384.f) + 1e-5f);
  u16* orow = out + (size_t)row * 384;
#pragma unroll
  for (int i = 0; i < 6; ++i) {
    int c = lane + (i << 6);
    orow[c] = f2bf((v[i] - mu) * rs * g[c] + b[c]);
  }
}

// ---------------- GEMM: out[M,N] = A[M,K](bf16) @ W[N,K]^T(bf16) + bias, epilogues ----------------
// EP 0: +bias -> bf16           (QKV)
// EP 1: +bias +res -> fp32      (proj + residual x)
// EP 2: +bias, gelu -> bf16     (FC1)
// EP 3: +bias +res -> fp32      (FC2 + residual x1)
// 1-D grid (nwg % 8 == 0), XCD-chunked swizzle, col-fastest within chunk.
// 2-phase double-buffered pipeline: STAGE(next) issued before COMPUTE(cur).
template <int EP>
__global__ __launch_bounds__(256, 2) void gemm_k(const u16* __restrict__ A,
                                                 const u16* __restrict__ W,
                                                 const float* __restrict__ bias,
                                                 const float* __restrict__ res,
                                                 void* __restrict__ outp,
                                                 int N, int K, int nCol) {
  __shared__ u16 As[2][128 * 64];
  __shared__ u16 Bs[2][128 * 64];
  const int tid = threadIdx.x;
  const int wave = tid >> 6, lane = tid & 63;
  // XCD swizzle: consecutive hardware ids round-robin XCDs; give each XCD a
  // contiguous chunk of logical tile ids (bijective since nwg % 8 == 0).
  const int nwg = gridDim.x;
  const int cpx = nwg >> 3;
  const int lin = (blockIdx.x & 7) * cpx + (blockIdx.x >> 3);
  const int rowT = lin / nCol;
  const int colT = lin - rowT * nCol;
  const int rowBase = rowT << 7;
  const int colBase = colT << 7;
  const int wr = (wave >> 1) << 6;
  const int wc = (wave & 1) << 6;
  f32x4 acc[4][4] = {};
  const int nK = K >> 6;
  const int r0 = tid >> 3;        // 0..31
  const int kb = (tid & 7) << 3;  // 0..56 (elements)
  const u16* Abase = A + (size_t)(rowBase + r0) * K + kb;
  const u16* Wbase = W + (size_t)(colBase + r0) * K + kb;

#define STAGE(buf, kt)                                                                   \
  {                                                                                      \
    const int k0_ = (kt) << 6;                                                           \
    _Pragma("unroll") for (int c = 0; c < 4; ++c) {                                      \
      gload16(Abase + (size_t)(c << 5) * K + k0_, &As[buf][((c << 5) + r0) * 64 + kb]);  \
      gload16(Wbase + (size_t)(c << 5) * K + k0_, &Bs[buf][((c << 5) + r0) * 64 + kb]);  \
    }                                                                                    \
  }

#define COMPUTE(buf)                                                                     \
  {                                                                                      \
    _Pragma("unroll") for (int kk = 0; kk < 2; ++kk) {                                   \
      bf16x8 af[4], bfr[4];                                                              \
      _Pragma("unroll") for (int m = 0; m < 4; ++m)                                      \
          af[m] = *(const bf16x8*)&As[buf][(wr + (m << 4) + (lane & 15)) * 64 +          \
                                           (kk << 5) + ((lane >> 4) << 3)];              \
      _Pragma("unroll") for (int n = 0; n < 4; ++n)                                      \
          bfr[n] = *(const bf16x8*)&Bs[buf][(wc + (n << 4) + (lane & 15)) * 64 +         \
                                            (kk << 5) + ((lane >> 4) << 3)];             \
      _Pragma("unroll") for (int m = 0; m < 4; ++m)                                      \
          _Pragma("unroll") for (int n = 0; n < 4; ++n)                                  \
              acc[m][n] =                                                                \
                  __builtin_amdgcn_mfma_f32_16x16x32_bf16(af[m], bfr[n], acc[m][n], 0, 0, 0); \
    }                                                                                    \
  }

  STAGE(0, 0);
  asm volatile("s_waitcnt vmcnt(0)" ::: "memory");
  __syncthreads();
  int cur = 0;
  for (int kt = 0; kt < nK - 1; ++kt) {
    STAGE(cur ^ 1, kt + 1);
    COMPUTE(cur);
    asm volatile("s_waitcnt vmcnt(0)" ::: "memory");
    __syncthreads();
    cur ^= 1;
  }
  COMPUTE(cur);
#undef STAGE
#undef COMPUTE

#pragma unroll
  for (int m = 0; m < 4; ++m) {
#pragma unroll
    for (int n = 0; n < 4; ++n) {
      const int col = colBase + wc + (n << 4) + (lane & 15);
      const int row0 = rowBase + wr + (m << 4) + ((lane >> 4) << 2);
      const float bv = bias[col];
#pragma unroll
      for (int j = 0; j < 4; ++j) {
        const size_t row = (size_t)(row0 + j);
        float y = acc[m][n][j] + bv;
        if (EP == 0) {
          ((u16*)outp)[row * N + col] = f2bf(y);
        } else if (EP == 1) {
          ((float*)outp)[row * N + col] = y + res[row * N + col];
        } else if (EP == 2) {
          y = 0.5f * y * (1.f + erff(y * 0.70710678118f));
          ((u16*)outp)[row * N + col] = f2bf(y);
        } else {
          ((float*)outp)[row * N + col] = y + res[row * N + col];
        }
      }
    }
  }
}

// ---------------- window attention: one block per (window, head) ----------------
__global__ __launch_bounds__(256) void attn_k(const u16* __restrict__ qkv,
                                              const float* __restrict__ bias_tab,
                                              u16* __restrict__ o) {
  const int blk = blockIdx.x;
  const int w = blk / NHEAD;
  const int h = blk - w * NHEAD;
  const int tid = threadIdx.x, wave = tid >> 6, lane = tid & 63;
  __shared__ u16 q_s[64 * 32];
  __shared__ u16 k_s[64 * 32];
  __shared__ u16 vt_s[32 * 64];      // transposed [d][key]
  __shared__ u16 p_s[4][16 * 72];    // per-wave P, padded stride 72
  const int b = w >> 6;
  const int wim = w & 63;
  const int wr0 = (wim >> 3) << 3, wc0 = (wim & 7) << 3;
  {
    const int r = tid >> 2, d0 = (tid & 3) << 3;
    const int pr = r >> 3, pc = r & 7;
    const int orow = (wr0 + pr + 4) & 63, ocol = (wc0 + pc + 4) & 63;
    const size_t t = ((size_t)b << 12) + (orow << 6) + ocol;
    const u16* base = qkv + t * 1152 + h * 32 + d0;
    *(uint4*)&q_s[r * 32 + d0] = *(const uint4*)(base);
    *(uint4*)&k_s[r * 32 + d0] = *(const uint4*)(base + 384);
    u16 vv[8];
    *(uint4*)vv = *(const uint4*)(base + 768);
#pragma unroll
    for (int j = 0; j < 8; ++j) vt_s[(d0 + j) * 64 + r] = vv[j];
  }
  __syncthreads();
  const int cIdx = lane & 15, rgrp = lane >> 4;
  const f32x4 zz = {0.f, 0.f, 0.f, 0.f};
  bf16x8 qa = *(const bf16x8*)&q_s[((wave << 4) + cIdx) * 32 + (rgrp << 3)];
  f32x4 s_acc[4];
#pragma unroll
  for (int n = 0; n < 4; ++n) {
    bf16x8 kb = *(const bf16x8*)&k_s[((n << 4) + cIdx) * 32 + (rgrp << 3)];
    s_acc[n] = __builtin_amdgcn_mfma_f32_16x16x32_bf16(qa, kb, zz, 0, 0, 0);
  }
  const float scale = 0.1767766952966369f;  // 1/sqrt(32)
  float mrow[4] = {-1e30f, -1e30f, -1e30f, -1e30f};
  const float* bt = bias_tab + h * 4096 + ((wave << 4) + (rgrp << 2)) * 64 + cIdx;
#pragma unroll
  for (int n = 0; n < 4; ++n)
#pragma unroll
    for (int j = 0; j < 4; ++j) {
      float val = s_acc[n][j] * scale + bt[j * 64 + (n << 4)];
      s_acc[n][j] = val;
      mrow[j] = fmaxf(mrow[j], val);
    }
#pragma unroll
  for (int j = 0; j < 4; ++j)
#pragma unroll
    for (int o2 = 1; o2 < 16; o2 <<= 1) mrow[j] = fmaxf(mrow[j], __shfl_xor(mrow[j], o2, 64));
  float srow[4] = {0.f, 0.f, 0.f, 0.f};
#pragma unroll
  for (int n = 0; n < 4; ++n)
#pragma unroll
    for (int j = 0; j < 4; ++j) {
      float e = __expf(s_acc[n][j] - mrow[j]);
      s_acc[n][j] = e;
      srow[j] += e;
    }
#pragma unroll
  for (int j = 0; j < 4; ++j)
#pragma unroll
    for (int o2 = 1; o2 < 16; o2 <<= 1) srow[j] += __shfl_xor(srow[j], o2, 64);
  float rinv[4];
#pragma unroll
  for (int j = 0; j < 4; ++j) rinv[j] = 1.f / srow[j];
  u16* pw = p_s[wave];
#pragma unroll
  for (int n = 0; n < 4; ++n)
#pragma unroll
    for (int j = 0; j < 4; ++j)
      pw[((rgrp << 2) + j) * 72 + (n << 4) + cIdx] = f2bf(s_acc[n][j] * rinv[j]);
  f32x4 o_acc[2] = {};
#pragma unroll
  for (int kk = 0; kk < 2; ++kk) {
    bf16x8 pa = *(const bf16x8*)&pw[cIdx * 72 + (kk << 5) + (rgrp << 3)];
#pragma unroll
    for (int c2 = 0; c2 < 2; ++c2) {
      bf16x8 vb = *(const bf16x8*)&vt_s[((c2 << 4) + cIdx) * 64 + (kk << 5) + (rgrp << 3)];
      o_acc[c2] = __builtin_amdgcn_mfma_f32_16x16x32_bf16(pa, vb, o_acc[c2], 0, 0, 0);
    }
  }
#pragma unroll
  for (int c2 = 0; c2 < 2; ++c2)
#pragma unroll
    for (int j = 0; j < 4; ++j) {
      const int p = (wave << 4) + (rgrp << 2) + j;
      const int pr = p >> 3, pc = p & 7;
      const int orow = (wr0 + pr + 4) & 63, ocol = (wc0 + pc + 4) & 63;
      const size_t t = ((size_t)b << 12) + (orow << 6) + ocol;
      o[t * 384 + h * 32 + (c2 << 4) + cIdx] = f2bf(o_acc[c2][j]);
    }
}

extern "C" void kernel_launch(void* const* d_in, const int* in_sizes, int n_in,
                              void* d_out, int out_size, void* d_ws, size_t ws_size,
                              hipStream_t stream) {
  const float* x = (const float*)d_in[0];
  const float* n1g = (const float*)d_in[1];
  const float* n1b = (const float*)d_in[2];
  const float* qkv_w = (const float*)d_in[3];
  const float* qkv_b = (const float*)d_in[4];
  const float* proj_w = (const float*)d_in[5];
  const float* proj_b = (const float*)d_in[6];
  const float* rpb = (const float*)d_in[7];
  const float* n2g = (const float*)d_in[8];
  const float* n2b = (const float*)d_in[9];
  const float* fc1_w = (const float*)d_in[10];
  const float* fc1_b = (const float*)d_in[11];
  const float* fc2_w = (const float*)d_in[12];
  const float* fc2_b = (const float*)d_in[13];

  char* ws = (char*)d_ws;
  u16* wqkv = (u16*)(ws + 0);                   // 884736 B
  u16* wproj = (u16*)(ws + 884736);             // 294912 B
  u16* wfc1 = (u16*)(ws + 1179648);             // 1179648 B
  u16* wfc2 = (u16*)(ws + 2359296);             // 1179648 B
  float* bias_tab = (float*)(ws + 3538944);     // 196608 B
  u16* qkv = (u16*)(ws + 3735552);              // region A: 201326592 B (qkv then m1)
  u16* m1 = qkv;
  u16* hbuf = (u16*)(ws + 205062144);           // region B: 50331648 B (h -> o -> h2)
  u16* obuf = hbuf;
  float* x1 = (float*)d_out;                    // x1 lives in d_out

  cvt_w<<<(442368 + 255) / 256, 256, 0, stream>>>(qkv_w, wqkv, 442368);
  cvt_w<<<(147456 + 255) / 256, 256, 0, stream>>>(proj_w, wproj, 147456);
  cvt_w<<<(589824 + 255) / 256, 256, 0, stream>>>(fc1_w, wfc1, 589824);
  cvt_w<<<(589824 + 255) / 256, 256, 0, stream>>>(fc2_w, wfc2, 589824);
  build_bias<<<192, 256, 0, stream>>>(rpb, bias_tab);

  ln_k<<<16384, 256, 0, stream>>>(x, n1g, n1b, hbuf);
  gemm_k<0><<<512 * 9, 256, 0, stream>>>(hbuf, wqkv, qkv_b, nullptr, qkv, 1152, 384, 9);
  attn_k<<<12288, 256, 0, stream>>>(qkv, bias_tab, obuf);
  gemm_k<1><<<512 * 3, 256, 0, stream>>>(obuf, wproj, proj_b, x, x1, 384, 384, 3);
  ln_k<<<16384, 256, 0, stream>>>(x1, n2g, n2b, hbuf);
  gemm_k<2><<<512 * 12, 256, 0, stream>>>(hbuf, wfc1, fc1_b, nullptr, m1, 1536, 384, 12);
  gemm_k<3><<<512 * 3, 256, 0, stream>>>(m1, wfc2, fc2_b, x1, (float*)d_out, 384, 1536, 3);
}

// Round 3
// 647.597 us; speedup vs baseline: 1.2152x; 1.0919x over previous
//
#include <hip/hip_runtime.h>
#include <hip/hip_bf16.h>
#include <math.h>

typedef __attribute__((ext_vector_type(8))) short bf16x8;
typedef __attribute__((ext_vector_type(4))) float f32x4;
typedef unsigned short u16;

#define NHEAD 12

__device__ __forceinline__ u16 f2bf(float f) {
  unsigned int u = __builtin_bit_cast(unsigned int, f);
  return (u16)((u + 0x7fffu + ((u >> 16) & 1u)) >> 16);
}

__device__ __forceinline__ void gload16(const void* g, void* l) {
  __builtin_amdgcn_global_load_lds(
      (const __attribute__((address_space(1))) void*)g,
      (__attribute__((address_space(3))) void*)l, 16, 0, 0);
}

// ---------------- all weights fp32 -> bf16, packed dst ----------------
__global__ void cvt_all(const float* __restrict__ s0, const float* __restrict__ s1,
                        const float* __restrict__ s2, const float* __restrict__ s3,
                        u16* __restrict__ d) {
  int i = blockIdx.x * 256 + threadIdx.x;  // total 1769472
  if (i >= 1769472) return;
  float v;
  if (i < 442368) v = s0[i];
  else if (i < 589824) v = s1[i - 442368];
  else if (i < 1179648) v = s2[i - 589824];
  else v = s3[i - 1179648];
  d[i] = f2bf(v);
}

// ---------------- relative-position bias table [12][64][64] ----------------
__global__ void build_bias(const float* __restrict__ rpb, float* __restrict__ bt) {
  int i = blockIdx.x * 256 + threadIdx.x;
  if (i >= NHEAD * 4096) return;
  int h = i >> 12;
  int q = (i >> 6) & 63;
  int k = i & 63;
  int qi = q >> 3, qj = q & 7, ki = k >> 3, kj = k & 7;
  int idx = (qi - ki + 7) * 15 + (qj - kj + 7);
  bt[i] = rpb[idx * NHEAD + h];
}

// ---------------- LayerNorm: fp32 in -> bf16 out, C=384, 1 wave/row ----------------
__global__ __launch_bounds__(256) void ln_k(const float* __restrict__ x,
                                            const float* __restrict__ g,
                                            const float* __restrict__ b,
                                            u16* __restrict__ out) {
  int row = (blockIdx.x << 2) + (threadIdx.x >> 6);
  int lane = threadIdx.x & 63;
  const float* xr = x + (size_t)row * 384;
  float v[6];
  float s = 0.f;
#pragma unroll
  for (int i = 0; i < 6; ++i) { v[i] = xr[lane + (i << 6)]; s += v[i]; }
#pragma unroll
  for (int o = 32; o; o >>= 1) s += __shfl_xor(s, o, 64);
  float mu = s * (1.f / 384.f);
  float vs = 0.f;
#pragma unroll
  for (int i = 0; i < 6; ++i) { float d0 = v[i] - mu; vs += d0 * d0; }
#pragma unroll
  for (int o = 32; o; o >>= 1) vs += __shfl_xor(vs, o, 64);
  float rs = rsqrtf(vs * (1.f / 384.f) + 1e-5f);
  u16* orow = out + (size_t)row * 384;
#pragma unroll
  for (int i = 0; i < 6; ++i) {
    int c = lane + (i << 6);
    orow[c] = f2bf((v[i] - mu) * rs * g[c] + b[c]);
  }
}

// ---------------- deep-pipelined GEMM ----------------
// out[M,N] = A[M,K](bf16) @ W[N,K]^T(bf16) + bias, epilogues:
// EP 0: +bias -> bf16 (QKV)   EP 1: +bias+res -> fp32 (proj)
// EP 2: +bias gelu -> bf16 (FC1)   EP 3: +bias+res -> fp32 (FC2)
// BM=256, BK=32, BN in {128,256}. 512 threads = 8 waves (2M x 4N).
// 4-deep LDS ring: loads issued 3 K-steps ahead; counted vmcnt (never drain in
// steady state); one raw s_barrier per K-step; T2 XOR swizzle (slot ^= row&3)
// realized via pre-swizzled global source + swizzled ds_read; T5 setprio.
template <int EP, int BN>
__global__ __launch_bounds__(512, 1) void gemm8(const u16* __restrict__ A,
                                                const u16* __restrict__ W,
                                                const float* __restrict__ bias,
                                                const float* __restrict__ res,
                                                void* __restrict__ outp,
                                                int N, int K, int nCol) {
  constexpr int NR = BN / 4;      // per-wave col span
  constexpr int NFRAG = NR / 16;  // 4 (BN=256) or 2 (BN=128)
  __shared__ u16 As[4][256 * 32];
  __shared__ u16 Bs[4][BN * 32];
  const int tid = threadIdx.x;
  const int wave = tid >> 6, lane = tid & 63;
  const int wm = wave >> 2, wn = wave & 3;
  const int nwg = gridDim.x;
  const int cpx = nwg >> 3;
  const int lin = (blockIdx.x & 7) * cpx + (blockIdx.x >> 3);
  const int rowT = lin / nCol;
  const int colT = lin - rowT * nCol;
  const int rowBase = rowT << 8;
  const int colBase = colT * BN;
  const int nK = K >> 5;

  // staging: thread t covers (row = rnd*128 + (t>>2), 16B block t&3); the
  // fetched global col-block is (t&3)^(row&3) so that a swizzled read
  // slot = (lane>>4)^(row&3) finds its data (involution on both sides).
  const int srow = tid >> 2;
  const int scb = (tid & 3) ^ (srow & 3);
  const u16* Asrc = A + (size_t)(rowBase + srow) * K + (scb << 3);
  const u16* Wsrc = W + (size_t)(colBase + srow) * K + (scb << 3);
  const int ldst = tid << 3;  // u16 idx, = byte t*16

  auto stage = [&](int j_) {
    const int b_ = j_ & 3;
    const size_t k0_ = (size_t)(j_ << 5);
    gload16(Asrc + k0_, &As[b_][ldst]);
    gload16(Asrc + (size_t)128 * K + k0_, &As[b_][4096 + ldst]);
    gload16(Wsrc + k0_, &Bs[b_][ldst]);
    if constexpr (BN == 256)
      gload16(Wsrc + (size_t)128 * K + k0_, &Bs[b_][4096 + ldst]);
  };

  // ds-read swizzle slot (u16 offset): row&3 == lane&3 for all fragments
  const int slot8 = (((lane >> 4) ^ (lane & 3)) << 3);
  const int arow0 = (wm << 7) + (lane & 15);
  const int brow0 = wn * NR + (lane & 15);

  f32x4 acc[8][NFRAG] = {};

  stage(0);
  stage(1);
  stage(2);
  for (int j = 0; j < nK; ++j) {
    const int buf = j & 3;
    const int rem = nK - 1 - j;
    if (rem >= 2) {
      if constexpr (BN == 256) asm volatile("s_waitcnt vmcnt(8)" ::: "memory");
      else                     asm volatile("s_waitcnt vmcnt(6)" ::: "memory");
    } else if (rem == 1) {
      if constexpr (BN == 256) asm volatile("s_waitcnt vmcnt(4)" ::: "memory");
      else                     asm volatile("s_waitcnt vmcnt(3)" ::: "memory");
    } else {
      asm volatile("s_waitcnt vmcnt(0)" ::: "memory");
    }
    __builtin_amdgcn_sched_barrier(0);
    __builtin_amdgcn_s_barrier();
    __builtin_amdgcn_sched_barrier(0);
    const u16* ab = As[buf];
    const u16* bb = Bs[buf];
    if (j + 3 < nK) stage(j + 3);
    // phase 0: B all frags + A m0..3
    bf16x8 bF[NFRAG];
#pragma unroll
    for (int n = 0; n < NFRAG; ++n)
      bF[n] = *(const bf16x8*)&bb[(brow0 + (n << 4)) * 32 + slot8];
    bf16x8 aF[4];
#pragma unroll
    for (int m = 0; m < 4; ++m)
      aF[m] = *(const bf16x8*)&ab[(arow0 + (m << 4)) * 32 + slot8];
    __builtin_amdgcn_s_setprio(1);
#pragma unroll
    for (int m = 0; m < 4; ++m)
#pragma unroll
      for (int n = 0; n < NFRAG; ++n)
        acc[m][n] = __builtin_amdgcn_mfma_f32_16x16x32_bf16(aF[m], bF[n], acc[m][n], 0, 0, 0);
    __builtin_amdgcn_s_setprio(0);
    __builtin_amdgcn_sched_barrier(0);
    // phase 1: A m4..7
#pragma unroll
    for (int m = 0; m < 4; ++m)
      aF[m] = *(const bf16x8*)&ab[(arow0 + 64 + (m << 4)) * 32 + slot8];
    __builtin_amdgcn_s_setprio(1);
#pragma unroll
    for (int m = 0; m < 4; ++m)
#pragma unroll
      for (int n = 0; n < NFRAG; ++n)
        acc[4 + m][n] = __builtin_amdgcn_mfma_f32_16x16x32_bf16(aF[m], bF[n], acc[4 + m][n], 0, 0, 0);
    __builtin_amdgcn_s_setprio(0);
    __builtin_amdgcn_sched_barrier(0);
  }

#pragma unroll
  for (int m = 0; m < 8; ++m) {
#pragma unroll
    for (int n = 0; n < NFRAG; ++n) {
      const int col = colBase + wn * NR + (n << 4) + (lane & 15);
      const int row0 = rowBase + (wm << 7) + (m << 4) + ((lane >> 4) << 2);
      const float bv = bias[col];
#pragma unroll
      for (int jj = 0; jj < 4; ++jj) {
        const size_t row = (size_t)(row0 + jj);
        float y = acc[m][n][jj] + bv;
        if (EP == 0) {
          ((u16*)outp)[row * N + col] = f2bf(y);
        } else if (EP == 1) {
          ((float*)outp)[row * N + col] = y + res[row * N + col];
        } else if (EP == 2) {
          // tanh-form gelu (max |err| vs exact erf-gelu ~3e-4)
          float u = 0.7978845608028654f * (y + 0.044715f * y * y * y);
          float t = 1.f - 2.f / (1.f + __expf(2.f * u));
          y = 0.5f * y * (1.f + t);
          ((u16*)outp)[row * N + col] = f2bf(y);
        } else {
          ((float*)outp)[row * N + col] = y + res[row * N + col];
        }
      }
    }
  }
}

// ---------------- window attention: one block per (window, head) ----------------
__global__ __launch_bounds__(256) void attn_k(const u16* __restrict__ qkv,
                                              const float* __restrict__ bias_tab,
                                              u16* __restrict__ o) {
  const int blk = blockIdx.x;
  const int w = blk / NHEAD;
  const int h = blk - w * NHEAD;
  const int tid = threadIdx.x, wave = tid >> 6, lane = tid & 63;
  __shared__ u16 q_s[64 * 32];
  __shared__ u16 k_s[64 * 32];
  __shared__ u16 vt_s[32 * 64];
  __shared__ u16 p_s[4][16 * 72];
  const int b = w >> 6;
  const int wim = w & 63;
  const int wr0 = (wim >> 3) << 3, wc0 = (wim & 7) << 3;
  {
    const int r = tid >> 2, d0 = (tid & 3) << 3;
    const int pr = r >> 3, pc = r & 7;
    const int orow = (wr0 + pr + 4) & 63, ocol = (wc0 + pc + 4) & 63;
    const size_t t = ((size_t)b << 12) + (orow << 6) + ocol;
    const u16* base = qkv + t * 1152 + h * 32 + d0;
    *(uint4*)&q_s[r * 32 + d0] = *(const uint4*)(base);
    *(uint4*)&k_s[r * 32 + d0] = *(const uint4*)(base + 384);
    u16 vv[8];
    *(uint4*)vv = *(const uint4*)(base + 768);
#pragma unroll
    for (int j = 0; j < 8; ++j) vt_s[(d0 + j) * 64 + r] = vv[j];
  }
  __syncthreads();
  const int cIdx = lane & 15, rgrp = lane >> 4;
  const f32x4 zz = {0.f, 0.f, 0.f, 0.f};
  bf16x8 qa = *(const bf16x8*)&q_s[((wave << 4) + cIdx) * 32 + (rgrp << 3)];
  f32x4 s_acc[4];
#pragma unroll
  for (int n = 0; n < 4; ++n) {
    bf16x8 kb = *(const bf16x8*)&k_s[((n << 4) + cIdx) * 32 + (rgrp << 3)];
    s_acc[n] = __builtin_amdgcn_mfma_f32_16x16x32_bf16(qa, kb, zz, 0, 0, 0);
  }
  const float scale = 0.1767766952966369f;
  float mrow[4] = {-1e30f, -1e30f, -1e30f, -1e30f};
  const float* bt = bias_tab + h * 4096 + ((wave << 4) + (rgrp << 2)) * 64 + cIdx;
#pragma unroll
  for (int n = 0; n < 4; ++n)
#pragma unroll
    for (int j = 0; j < 4; ++j) {
      float val = s_acc[n][j] * scale + bt[j * 64 + (n << 4)];
      s_acc[n][j] = val;
      mrow[j] = fmaxf(mrow[j], val);
    }
#pragma unroll
  for (int j = 0; j < 4; ++j)
#pragma unroll
    for (int o2 = 1; o2 < 16; o2 <<= 1) mrow[j] = fmaxf(mrow[j], __shfl_xor(mrow[j], o2, 64));
  float srow[4] = {0.f, 0.f, 0.f, 0.f};
#pragma unroll
  for (int n = 0; n < 4; ++n)
#pragma unroll
    for (int j = 0; j < 4; ++j) {
      float e = __expf(s_acc[n][j] - mrow[j]);
      s_acc[n][j] = e;
      srow[j] += e;
    }
#pragma unroll
  for (int j = 0; j < 4; ++j)
#pragma unroll
    for (int o2 = 1; o2 < 16; o2 <<= 1) srow[j] += __shfl_xor(srow[j], o2, 64);
  float rinv[4];
#pragma unroll
  for (int j = 0; j < 4; ++j) rinv[j] = 1.f / srow[j];
  u16* pw = p_s[wave];
#pragma unroll
  for (int n = 0; n < 4; ++n)
#pragma unroll
    for (int j = 0; j < 4; ++j)
      pw[((rgrp << 2) + j) * 72 + (n << 4) + cIdx] = f2bf(s_acc[n][j] * rinv[j]);
  f32x4 o_acc[2] = {};
#pragma unroll
  for (int kk = 0; kk < 2; ++kk) {
    bf16x8 pa = *(const bf16x8*)&pw[cIdx * 72 + (kk << 5) + (rgrp << 3)];
#pragma unroll
    for (int c2 = 0; c2 < 2; ++c2) {
      bf16x8 vb = *(const bf16x8*)&vt_s[((c2 << 4) + cIdx) * 64 + (kk << 5) + (rgrp << 3)];
      o_acc[c2] = __builtin_amdgcn_mfma_f32_16x16x32_bf16(pa, vb, o_acc[c2], 0, 0, 0);
    }
  }
#pragma unroll
  for (int c2 = 0; c2 < 2; ++c2)
#pragma unroll
    for (int j = 0; j < 4; ++j) {
      const int p = (wave << 4) + (rgrp << 2) + j;
      const int pr = p >> 3, pc = p & 7;
      const int orow = (wr0 + pr + 4) & 63, ocol = (wc0 + pc + 4) & 63;
      const size_t t = ((size_t)b << 12) + (orow << 6) + ocol;
      o[t * 384 + h * 32 + (c2 << 4) + cIdx] = f2bf(o_acc[c2][j]);
    }
}

extern "C" void kernel_launch(void* const* d_in, const int* in_sizes, int n_in,
                              void* d_out, int out_size, void* d_ws, size_t ws_size,
                              hipStream_t stream) {
  const float* x = (const float*)d_in[0];
  const float* n1g = (const float*)d_in[1];
  const float* n1b = (const float*)d_in[2];
  const float* qkv_w = (const float*)d_in[3];
  const float* qkv_b = (const float*)d_in[4];
  const float* proj_w = (const float*)d_in[5];
  const float* proj_b = (const float*)d_in[6];
  const float* rpb = (const float*)d_in[7];
  const float* n2g = (const float*)d_in[8];
  const float* n2b = (const float*)d_in[9];
  const float* fc1_w = (const float*)d_in[10];
  const float* fc1_b = (const float*)d_in[11];
  const float* fc2_w = (const float*)d_in[12];
  const float* fc2_b = (const float*)d_in[13];

  char* ws = (char*)d_ws;
  u16* wqkv = (u16*)(ws + 0);                // 442368 elems
  u16* wproj = (u16*)(ws + 884736);          // 147456
  u16* wfc1 = (u16*)(ws + 1179648);          // 589824
  u16* wfc2 = (u16*)(ws + 2359296);          // 589824
  float* bias_tab = (float*)(ws + 3538944);
  u16* qkv = (u16*)(ws + 3735552);           // region A (qkv, then m1)
  u16* m1 = qkv;
  u16* hbuf = (u16*)(ws + 205062144);        // region B (h -> o -> h2)
  u16* obuf = hbuf;
  float* x1 = (float*)d_out;

  cvt_all<<<(1769472 + 255) / 256, 256, 0, stream>>>(qkv_w, proj_w, fc1_w, fc2_w, wqkv);
  build_bias<<<192, 256, 0, stream>>>(rpb, bias_tab);

  ln_k<<<16384, 256, 0, stream>>>(x, n1g, n1b, hbuf);
  gemm8<0, 128><<<2304, 512, 0, stream>>>(hbuf, wqkv, qkv_b, nullptr, qkv, 1152, 384, 9);
  attn_k<<<12288, 256, 0, stream>>>(qkv, bias_tab, obuf);
  gemm8<1, 128><<<768, 512, 0, stream>>>(obuf, wproj, proj_b, x, x1, 384, 384, 3);
  ln_k<<<16384, 256, 0, stream>>>(x1, n2g, n2b, hbuf);
  gemm8<2, 256><<<1536, 512, 0, stream>>>(hbuf, wfc1, fc1_b, nullptr, m1, 1536, 384, 6);
  gemm8<3, 128><<<768, 512, 0, stream>>>(m1, wfc2, fc2_b, x1, (float*)d_out, 384, 1536, 3);
}

// Round 4
// 547.306 us; speedup vs baseline: 1.4379x; 1.1832x over previous
//
#include <hip/hip_runtime.h>
#include <hip/hip_bf16.h>
#include <math.h>

typedef __attribute__((ext_vector_type(8))) short bf16x8;
typedef __attribute__((ext_vector_type(4))) float f32x4;
typedef unsigned short u16;

#define NHEAD 12

__device__ __forceinline__ u16 f2bf(float f) {
  unsigned int u = __builtin_bit_cast(unsigned int, f);
  return (u16)((u + 0x7fffu + ((u >> 16) & 1u)) >> 16);
}

__device__ __forceinline__ void gload16(const void* g, void* l) {
  __builtin_amdgcn_global_load_lds(
      (const __attribute__((address_space(1))) void*)g,
      (__attribute__((address_space(3))) void*)l, 16, 0, 0);
}

// ---------------- all weights fp32 -> bf16, packed dst ----------------
__global__ void cvt_all(const float* __restrict__ s0, const float* __restrict__ s1,
                        const float* __restrict__ s2, const float* __restrict__ s3,
                        u16* __restrict__ d) {
  int i = blockIdx.x * 256 + threadIdx.x;  // total 1769472
  if (i >= 1769472) return;
  float v;
  if (i < 442368) v = s0[i];
  else if (i < 589824) v = s1[i - 442368];
  else if (i < 1179648) v = s2[i - 589824];
  else v = s3[i - 1179648];
  d[i] = f2bf(v);
}

// ---------------- relative-position bias table [12][64][64] ----------------
__global__ void build_bias(const float* __restrict__ rpb, float* __restrict__ bt) {
  int i = blockIdx.x * 256 + threadIdx.x;
  if (i >= NHEAD * 4096) return;
  int h = i >> 12;
  int q = (i >> 6) & 63;
  int k = i & 63;
  int qi = q >> 3, qj = q & 7, ki = k >> 3, kj = k & 7;
  int idx = (qi - ki + 7) * 15 + (qj - kj + 7);
  bt[i] = rpb[idx * NHEAD + h];
}

// ---------------- LayerNorm: fp32 in -> bf16 out, C=384, 1 wave/row ----------------
__global__ __launch_bounds__(256) void ln_k(const float* __restrict__ x,
                                            const float* __restrict__ g,
                                            const float* __restrict__ b,
                                            u16* __restrict__ out) {
  int row = (blockIdx.x << 2) + (threadIdx.x >> 6);
  int lane = threadIdx.x & 63;
  const float* xr = x + (size_t)row * 384;
  float v[6];
  float s = 0.f;
#pragma unroll
  for (int i = 0; i < 6; ++i) { v[i] = xr[lane + (i << 6)]; s += v[i]; }
#pragma unroll
  for (int o = 32; o; o >>= 1) s += __shfl_xor(s, o, 64);
  float mu = s * (1.f / 384.f);
  float vs = 0.f;
#pragma unroll
  for (int i = 0; i < 6; ++i) { float d0 = v[i] - mu; vs += d0 * d0; }
#pragma unroll
  for (int o = 32; o; o >>= 1) vs += __shfl_xor(vs, o, 64);
  float rs = rsqrtf(vs * (1.f / 384.f) + 1e-5f);
  u16* orow = out + (size_t)row * 384;
#pragma unroll
  for (int i = 0; i < 6; ++i) {
    int c = lane + (i << 6);
    orow[c] = f2bf((v[i] - mu) * rs * g[c] + b[c]);
  }
}

// ---------------- deep-pipelined GEMM ----------------
// out[M,N] = A[M,K](bf16) @ W[N,K]^T(bf16) + bias, epilogues:
// EP 0: +bias -> bf16 (QKV)   EP 1: +bias+res -> fp32 (proj)
// EP 2: +bias gelu -> bf16 (FC1)   EP 3: +bias+res -> fp32 (FC2)
// BM=256, BN=128, BK=32. 512 threads = 8 waves (4M x 2N).
// 3-deep LDS ring (72 KB -> 2 blocks/CU): loads issued 2 K-steps ahead;
// counted vmcnt(3); one raw s_barrier per K-step; XOR swizzle
// slot = cb ^ ((row>>1)&3) (bank-bijective per 8 rows); T5 setprio.
template <int EP>
__global__ __launch_bounds__(512, 4) void gemm8(const u16* __restrict__ A,
                                                const u16* __restrict__ W,
                                                const float* __restrict__ bias,
                                                const float* __restrict__ res,
                                                void* __restrict__ outp,
                                                int N, int K, int nCol) {
  __shared__ u16 As[3][256 * 32];
  __shared__ u16 Bs[3][128 * 32];
  const int tid = threadIdx.x;
  const int wave = tid >> 6, lane = tid & 63;
  const int wm = wave >> 1, wn = wave & 1;
  const int nwg = gridDim.x;
  const int cpx = nwg >> 3;
  const int lin = (blockIdx.x & 7) * cpx + (blockIdx.x >> 3);
  const int rowT = lin / nCol;
  const int colT = lin - rowT * nCol;
  const int rowBase = rowT << 8;
  const int colBase = colT << 7;
  const int nK = K >> 5;

  // staging: thread t covers (row = t>>2, 16B slot t&3); fetched global
  // col-block = (t&3) ^ ((row>>1)&3) so a read at slot = cb ^ ((row>>1)&3)
  // finds col-block cb (same XOR involution both sides).
  const int srow = tid >> 2;
  const int scb = (tid & 3) ^ ((tid >> 3) & 3);
  const u16* Asrc = A + (size_t)(rowBase + srow) * K + (scb << 3);
  const u16* Wsrc = W + (size_t)(colBase + srow) * K + (scb << 3);
  const int ldst = tid << 3;  // u16 idx = byte t*16

  auto stage = [&](int j_, int b_) {
    const size_t k0_ = (size_t)(j_ << 5);
    gload16(Asrc + k0_, &As[b_][ldst]);
    gload16(Asrc + (size_t)128 * K + k0_, &As[b_][4096 + ldst]);
    gload16(Wsrc + k0_, &Bs[b_][ldst]);
  };

  // read slot: cb = lane>>4 (k-offset group), row parity bits = (lane>>1)&3
  const int slot8 = (((lane >> 4) ^ ((lane >> 1) & 3)) << 3);
  const int arow0 = (wm << 6) + (lane & 15);
  const int brow0 = (wn << 6) + (lane & 15);

  f32x4 acc[4][4] = {};

  stage(0, 0);
  stage(1, 1);
  int bj = 0, bs = 2;
  for (int j = 0; j < nK; ++j) {
    if (j < nK - 1) asm volatile("s_waitcnt vmcnt(3)" ::: "memory");
    else            asm volatile("s_waitcnt vmcnt(0)" ::: "memory");
    __builtin_amdgcn_sched_barrier(0);
    __builtin_amdgcn_s_barrier();
    __builtin_amdgcn_sched_barrier(0);
    if (j + 2 < nK) stage(j + 2, bs);
    const u16* ab = As[bj];
    const u16* bb = Bs[bj];
    bf16x8 aF[4], bF[2];
#pragma unroll
    for (int m = 0; m < 4; ++m)
      aF[m] = *(const bf16x8*)&ab[(arow0 + (m << 4)) * 32 + slot8];
#pragma unroll
    for (int n = 0; n < 2; ++n)
      bF[n] = *(const bf16x8*)&bb[(brow0 + (n << 4)) * 32 + slot8];
    __builtin_amdgcn_s_setprio(1);
#pragma unroll
    for (int m = 0; m < 4; ++m)
#pragma unroll
      for (int n = 0; n < 2; ++n)
        acc[m][n] = __builtin_amdgcn_mfma_f32_16x16x32_bf16(aF[m], bF[n], acc[m][n], 0, 0, 0);
    __builtin_amdgcn_s_setprio(0);
#pragma unroll
    for (int n = 0; n < 2; ++n)
      bF[n] = *(const bf16x8*)&bb[(brow0 + ((n + 2) << 4)) * 32 + slot8];
    __builtin_amdgcn_s_setprio(1);
#pragma unroll
    for (int m = 0; m < 4; ++m)
#pragma unroll
      for (int n = 0; n < 2; ++n)
        acc[m][n + 2] = __builtin_amdgcn_mfma_f32_16x16x32_bf16(aF[m], bF[n], acc[m][n + 2], 0, 0, 0);
    __builtin_amdgcn_s_setprio(0);
    __builtin_amdgcn_sched_barrier(0);
    bj = (bj == 2) ? 0 : bj + 1;
    bs = (bs == 2) ? 0 : bs + 1;
  }

#pragma unroll
  for (int m = 0; m < 4; ++m) {
#pragma unroll
    for (int n = 0; n < 4; ++n) {
      const int col = colBase + (wn << 6) + (n << 4) + (lane & 15);
      const int row0 = rowBase + (wm << 6) + (m << 4) + ((lane >> 4) << 2);
      const float bv = bias[col];
#pragma unroll
      for (int jj = 0; jj < 4; ++jj) {
        const size_t row = (size_t)(row0 + jj);
        float y = acc[m][n][jj] + bv;
        if (EP == 0) {
          ((u16*)outp)[row * N + col] = f2bf(y);
        } else if (EP == 1) {
          ((float*)outp)[row * N + col] = y + res[row * N + col];
        } else if (EP == 2) {
          // tanh-form gelu (max |err| vs exact erf-gelu ~3e-4)
          float u = 0.7978845608028654f * (y + 0.044715f * y * y * y);
          float t = 1.f - 2.f / (1.f + __expf(2.f * u));
          y = 0.5f * y * (1.f + t);
          ((u16*)outp)[row * N + col] = f2bf(y);
        } else {
          ((float*)outp)[row * N + col] = y + res[row * N + col];
        }
      }
    }
  }
}

// ---------------- window attention: one block per (window, head) ----------------
// XCD swizzle: 12 consecutive logical ids (= the 12 heads of one window) land
// in one XCD chunk so they share the window's qkv rows in that XCD's L2.
__global__ __launch_bounds__(256) void attn_k(const u16* __restrict__ qkv,
                                              const float* __restrict__ bias_tab,
                                              u16* __restrict__ o) {
  const int cpx = gridDim.x >> 3;
  const int lin = (blockIdx.x & 7) * cpx + (blockIdx.x >> 3);
  const int w = lin / NHEAD;
  const int h = lin - w * NHEAD;
  const int tid = threadIdx.x, wave = tid >> 6, lane = tid & 63;
  __shared__ u16 q_s[64 * 32];
  __shared__ u16 k_s[64 * 32];
  __shared__ u16 vt_s[32 * 64];
  __shared__ u16 p_s[4][16 * 72];
  const int b = w >> 6;
  const int wim = w & 63;
  const int wr0 = (wim >> 3) << 3, wc0 = (wim & 7) << 3;
  {
    const int r = tid >> 2, d0 = (tid & 3) << 3;
    const int pr = r >> 3, pc = r & 7;
    const int orow = (wr0 + pr + 4) & 63, ocol = (wc0 + pc + 4) & 63;
    const size_t t = ((size_t)b << 12) + (orow << 6) + ocol;
    const u16* base = qkv + t * 1152 + h * 32 + d0;
    *(uint4*)&q_s[r * 32 + d0] = *(const uint4*)(base);
    *(uint4*)&k_s[r * 32 + d0] = *(const uint4*)(base + 384);
    u16 vv[8];
    *(uint4*)vv = *(const uint4*)(base + 768);
#pragma unroll
    for (int j = 0; j < 8; ++j) vt_s[(d0 + j) * 64 + r] = vv[j];
  }
  __syncthreads();
  const int cIdx = lane & 15, rgrp = lane >> 4;
  const f32x4 zz = {0.f, 0.f, 0.f, 0.f};
  bf16x8 qa = *(const bf16x8*)&q_s[((wave << 4) + cIdx) * 32 + (rgrp << 3)];
  f32x4 s_acc[4];
#pragma unroll
  for (int n = 0; n < 4; ++n) {
    bf16x8 kb = *(const bf16x8*)&k_s[((n << 4) + cIdx) * 32 + (rgrp << 3)];
    s_acc[n] = __builtin_amdgcn_mfma_f32_16x16x32_bf16(qa, kb, zz, 0, 0, 0);
  }
  const float scale = 0.1767766952966369f;
  float mrow[4] = {-1e30f, -1e30f, -1e30f, -1e30f};
  const float* bt = bias_tab + h * 4096 + ((wave << 4) + (rgrp << 2)) * 64 + cIdx;
#pragma unroll
  for (int n = 0; n < 4; ++n)
#pragma unroll
    for (int j = 0; j < 4; ++j) {
      float val = s_acc[n][j] * scale + bt[j * 64 + (n << 4)];
      s_acc[n][j] = val;
      mrow[j] = fmaxf(mrow[j], val);
    }
#pragma unroll
  for (int j = 0; j < 4; ++j)
#pragma unroll
    for (int o2 = 1; o2 < 16; o2 <<= 1) mrow[j] = fmaxf(mrow[j], __shfl_xor(mrow[j], o2, 64));
  float srow[4] = {0.f, 0.f, 0.f, 0.f};
#pragma unroll
  for (int n = 0; n < 4; ++n)
#pragma unroll
    for (int j = 0; j < 4; ++j) {
      float e = __expf(s_acc[n][j] - mrow[j]);
      s_acc[n][j] = e;
      srow[j] += e;
    }
#pragma unroll
  for (int j = 0; j < 4; ++j)
#pragma unroll
    for (int o2 = 1; o2 < 16; o2 <<= 1) srow[j] += __shfl_xor(srow[j], o2, 64);
  float rinv[4];
#pragma unroll
  for (int j = 0; j < 4; ++j) rinv[j] = 1.f / srow[j];
  u16* pw = p_s[wave];
#pragma unroll
  for (int n = 0; n < 4; ++n)
#pragma unroll
    for (int j = 0; j < 4; ++j)
      pw[((rgrp << 2) + j) * 72 + (n << 4) + cIdx] = f2bf(s_acc[n][j] * rinv[j]);
  f32x4 o_acc[2] = {};
#pragma unroll
  for (int kk = 0; kk < 2; ++kk) {
    bf16x8 pa = *(const bf16x8*)&pw[cIdx * 72 + (kk << 5) + (rgrp << 3)];
#pragma unroll
    for (int c2 = 0; c2 < 2; ++c2) {
      bf16x8 vb = *(const bf16x8*)&vt_s[((c2 << 4) + cIdx) * 64 + (kk << 5) + (rgrp << 3)];
      o_acc[c2] = __builtin_amdgcn_mfma_f32_16x16x32_bf16(pa, vb, o_acc[c2], 0, 0, 0);
    }
  }
#pragma unroll
  for (int c2 = 0; c2 < 2; ++c2)
#pragma unroll
    for (int j = 0; j < 4; ++j) {
      const int p = (wave << 4) + (rgrp << 2) + j;
      const int pr = p >> 3, pc = p & 7;
      const int orow = (wr0 + pr + 4) & 63, ocol = (wc0 + pc + 4) & 63;
      const size_t t = ((size_t)b << 12) + (orow << 6) + ocol;
      o[t * 384 + h * 32 + (c2 << 4) + cIdx] = f2bf(o_acc[c2][j]);
    }
}

extern "C" void kernel_launch(void* const* d_in, const int* in_sizes, int n_in,
                              void* d_out, int out_size, void* d_ws, size_t ws_size,
                              hipStream_t stream) {
  const float* x = (const float*)d_in[0];
  const float* n1g = (const float*)d_in[1];
  const float* n1b = (const float*)d_in[2];
  const float* qkv_w = (const float*)d_in[3];
  const float* qkv_b = (const float*)d_in[4];
  const float* proj_w = (const float*)d_in[5];
  const float* proj_b = (const float*)d_in[6];
  const float* rpb = (const float*)d_in[7];
  const float* n2g = (const float*)d_in[8];
  const float* n2b = (const float*)d_in[9];
  const float* fc1_w = (const float*)d_in[10];
  const float* fc1_b = (const float*)d_in[11];
  const float* fc2_w = (const float*)d_in[12];
  const float* fc2_b = (const float*)d_in[13];

  char* ws = (char*)d_ws;
  u16* wqkv = (u16*)(ws + 0);                // 442368 elems
  u16* wproj = (u16*)(ws + 884736);          // 147456
  u16* wfc1 = (u16*)(ws + 1179648);          // 589824
  u16* wfc2 = (u16*)(ws + 2359296);          // 589824
  float* bias_tab = (float*)(ws + 3538944);
  u16* qkv = (u16*)(ws + 3735552);           // region A (qkv, then m1)
  u16* m1 = qkv;
  u16* hbuf = (u16*)(ws + 205062144);        // region B (h -> o -> h2)
  u16* obuf = hbuf;
  float* x1 = (float*)d_out;

  cvt_all<<<(1769472 + 255) / 256, 256, 0, stream>>>(qkv_w, proj_w, fc1_w, fc2_w, wqkv);
  build_bias<<<192, 256, 0, stream>>>(rpb, bias_tab);

  ln_k<<<16384, 256, 0, stream>>>(x, n1g, n1b, hbuf);
  gemm8<0><<<2304, 512, 0, stream>>>(hbuf, wqkv, qkv_b, nullptr, qkv, 1152, 384, 9);
  attn_k<<<12288, 256, 0, stream>>>(qkv, bias_tab, obuf);
  gemm8<1><<<768, 512, 0, stream>>>(obuf, wproj, proj_b, x, x1, 384, 384, 3);
  ln_k<<<16384, 256, 0, stream>>>(x1, n2g, n2b, hbuf);
  gemm8<2><<<3072, 512, 0, stream>>>(hbuf, wfc1, fc1_b, nullptr, m1, 1536, 384, 12);
  gemm8<3><<<768, 512, 0, stream>>>(m1, wfc2, fc2_b, x1, (float*)d_out, 384, 1536, 3);
}

// Round 5
// 507.486 us; speedup vs baseline: 1.5507x; 1.0785x over previous
//
#include <hip/hip_runtime.h>
#include <hip/hip_bf16.h>
#include <math.h>

typedef __attribute__((ext_vector_type(8))) short bf16x8;
typedef __attribute__((ext_vector_type(4))) float f32x4;
typedef unsigned short u16;

#define NHEAD 12

__device__ __forceinline__ u16 f2bf(float f) {
  unsigned int u = __builtin_bit_cast(unsigned int, f);
  return (u16)((u + 0x7fffu + ((u >> 16) & 1u)) >> 16);
}

__device__ __forceinline__ void gload16(const void* g, void* l) {
  __builtin_amdgcn_global_load_lds(
      (const __attribute__((address_space(1))) void*)g,
      (__attribute__((address_space(3))) void*)l, 16, 0, 0);
}

// ---------------- all weights fp32 -> bf16, packed dst ----------------
__global__ void cvt_all(const float* __restrict__ s0, const float* __restrict__ s1,
                        const float* __restrict__ s2, const float* __restrict__ s3,
                        u16* __restrict__ d) {
  int i = blockIdx.x * 256 + threadIdx.x;  // total 1769472
  if (i >= 1769472) return;
  float v;
  if (i < 442368) v = s0[i];
  else if (i < 589824) v = s1[i - 442368];
  else if (i < 1179648) v = s2[i - 589824];
  else v = s3[i - 1179648];
  d[i] = f2bf(v);
}

// ---------------- relative-position bias table [12][64][64] ----------------
__global__ void build_bias(const float* __restrict__ rpb, float* __restrict__ bt) {
  int i = blockIdx.x * 256 + threadIdx.x;
  if (i >= NHEAD * 4096) return;
  int h = i >> 12;
  int q = (i >> 6) & 63;
  int k = i & 63;
  int qi = q >> 3, qj = q & 7, ki = k >> 3, kj = k & 7;
  int idx = (qi - ki + 7) * 15 + (qj - kj + 7);
  bt[i] = rpb[idx * NHEAD + h];
}

// ---------------- LayerNorm: fp32 in -> bf16 out, C=384, 1 wave/row ----------------
__global__ __launch_bounds__(256) void ln_k(const float* __restrict__ x,
                                            const float* __restrict__ g,
                                            const float* __restrict__ b,
                                            u16* __restrict__ out) {
  int row = (blockIdx.x << 2) + (threadIdx.x >> 6);
  int lane = threadIdx.x & 63;
  const float* xr = x + (size_t)row * 384;
  float v[6];
  float s = 0.f;
#pragma unroll
  for (int i = 0; i < 6; ++i) { v[i] = xr[lane + (i << 6)]; s += v[i]; }
#pragma unroll
  for (int o = 32; o; o >>= 1) s += __shfl_xor(s, o, 64);
  float mu = s * (1.f / 384.f);
  float vs = 0.f;
#pragma unroll
  for (int i = 0; i < 6; ++i) { float d0 = v[i] - mu; vs += d0 * d0; }
#pragma unroll
  for (int o = 32; o; o >>= 1) vs += __shfl_xor(vs, o, 64);
  float rs = rsqrtf(vs * (1.f / 384.f) + 1e-5f);
  u16* orow = out + (size_t)row * 384;
#pragma unroll
  for (int i = 0; i < 6; ++i) {
    int c = lane + (i << 6);
    orow[c] = f2bf((v[i] - mu) * rs * g[c] + b[c]);
  }
}

// ---------------- m97-style GEMM ----------------
// out[M,N] = A[M,K](bf16) @ W[N,K]^T(bf16) + bias, epilogues:
// EP 0: +bias -> bf16 (QKV)   EP 1: +bias+res -> fp32 (proj)
// EP 2: +bias gelu -> bf16 (FC1)   EP 3: +bias+res -> fp32 (FC2)
// 128x128 tile, BK=64, 256 threads = 4 waves (2x2), single 32KB LDS buffer,
// 2 barriers per K-step. 3 blocks/CU staggered phases hide the barrier drain.
// XOR swizzle: row r, 16B slot s holds global col-block s^(r&7); read at
// slot (kk*4 + (lane>>4)) ^ (r&7).
template <int EP>
__global__ __launch_bounds__(256, 3) void gemmA(const u16* __restrict__ A,
                                                const u16* __restrict__ W,
                                                const float* __restrict__ bias,
                                                const float* __restrict__ res,
                                                void* __restrict__ outp,
                                                int N, int K, int nCol) {
  __shared__ u16 As[128 * 64];
  __shared__ u16 Bs[128 * 64];
  const int tid = threadIdx.x;
  const int wave = tid >> 6, lane = tid & 63;
  const int wm = wave >> 1, wn = wave & 1;
  const int nwg = gridDim.x, cpx = nwg >> 3;
  const int lin = (blockIdx.x & 7) * cpx + (blockIdx.x >> 3);
  const int rowT = lin / nCol;
  const int colT = lin - rowT * nCol;
  const int rowBase = rowT << 7;
  const int colBase = colT << 7;
  const int nK = K >> 6;

  // staging: round c covers rows c*32 + (tid>>3), slot s = tid&7; the fetched
  // global 16B col-block is s ^ (row&7) = (tid&7) ^ ((tid>>3)&7).
  const int g16 = (tid & 7) ^ ((tid >> 3) & 7);
  const u16* Asrc = A + (size_t)(rowBase + (tid >> 3)) * K + (g16 << 3);
  const u16* Wsrc = W + (size_t)(colBase + (tid >> 3)) * K + (g16 << 3);
  const int ldst = tid << 3;  // u16 idx; +c*2048 per round

  // fragment read slot: pre-slot = kk*4 + (lane>>4), XOR row&7 = lane&7
  const int q4 = lane >> 4;
  const int rx = lane & 7;
  const int arow = (wm << 6) + (lane & 15);
  const int brow = (wn << 6) + (lane & 15);

  f32x4 acc[4][4] = {};

  for (int j = 0; j < nK; ++j) {
    const size_t k0 = (size_t)j << 6;
#pragma unroll
    for (int c = 0; c < 4; ++c) {
      gload16(Asrc + (size_t)(c << 5) * K + k0, &As[(c << 11) + ldst]);
      gload16(Wsrc + (size_t)(c << 5) * K + k0, &Bs[(c << 11) + ldst]);
    }
    __syncthreads();
#pragma unroll
    for (int kk = 0; kk < 2; ++kk) {
      const int slot = (((kk << 2) + q4) ^ rx) << 3;
      bf16x8 aF[4], bF[4];
#pragma unroll
      for (int m = 0; m < 4; ++m)
        aF[m] = *(const bf16x8*)&As[(arow + (m << 4)) * 64 + slot];
#pragma unroll
      for (int n = 0; n < 4; ++n)
        bF[n] = *(const bf16x8*)&Bs[(brow + (n << 4)) * 64 + slot];
#pragma unroll
      for (int m = 0; m < 4; ++m)
#pragma unroll
        for (int n = 0; n < 4; ++n)
          acc[m][n] = __builtin_amdgcn_mfma_f32_16x16x32_bf16(aF[m], bF[n], acc[m][n], 0, 0, 0);
    }
    __syncthreads();
  }

#pragma unroll
  for (int m = 0; m < 4; ++m) {
#pragma unroll
    for (int n = 0; n < 4; ++n) {
      const int col = colBase + (wn << 6) + (n << 4) + (lane & 15);
      const int row0 = rowBase + (wm << 6) + (m << 4) + ((lane >> 4) << 2);
      const float bv = bias[col];
#pragma unroll
      for (int jj = 0; jj < 4; ++jj) {
        const size_t row = (size_t)(row0 + jj);
        float y = acc[m][n][jj] + bv;
        if (EP == 0) {
          ((u16*)outp)[row * N + col] = f2bf(y);
        } else if (EP == 1) {
          ((float*)outp)[row * N + col] = y + res[row * N + col];
        } else if (EP == 2) {
          // tanh-form gelu (max |err| vs exact erf-gelu ~3e-4)
          float u = 0.7978845608028654f * (y + 0.044715f * y * y * y);
          float t = 1.f - 2.f / (1.f + __expf(2.f * u));
          y = 0.5f * y * (1.f + t);
          ((u16*)outp)[row * N + col] = f2bf(y);
        } else {
          ((float*)outp)[row * N + col] = y + res[row * N + col];
        }
      }
    }
  }
}

// ---------------- window attention: one block per (window, head) ----------------
// XCD swizzle: 12 consecutive logical ids (= the 12 heads of one window) land
// in one XCD chunk so they share the window's qkv rows in that XCD's L2.
__global__ __launch_bounds__(256) void attn_k(const u16* __restrict__ qkv,
                                              const float* __restrict__ bias_tab,
                                              u16* __restrict__ o) {
  const int cpx = gridDim.x >> 3;
  const int lin = (blockIdx.x & 7) * cpx + (blockIdx.x >> 3);
  const int w = lin / NHEAD;
  const int h = lin - w * NHEAD;
  const int tid = threadIdx.x, wave = tid >> 6, lane = tid & 63;
  __shared__ u16 q_s[64 * 32];
  __shared__ u16 k_s[64 * 32];
  __shared__ u16 vt_s[32 * 64];
  __shared__ u16 p_s[4][16 * 72];
  const int b = w >> 6;
  const int wim = w & 63;
  const int wr0 = (wim >> 3) << 3, wc0 = (wim & 7) << 3;
  {
    const int r = tid >> 2, d0 = (tid & 3) << 3;
    const int pr = r >> 3, pc = r & 7;
    const int orow = (wr0 + pr + 4) & 63, ocol = (wc0 + pc + 4) & 63;
    const size_t t = ((size_t)b << 12) + (orow << 6) + ocol;
    const u16* base = qkv + t * 1152 + h * 32 + d0;
    *(uint4*)&q_s[r * 32 + d0] = *(const uint4*)(base);
    *(uint4*)&k_s[r * 32 + d0] = *(const uint4*)(base + 384);
    u16 vv[8];
    *(uint4*)vv = *(const uint4*)(base + 768);
#pragma unroll
    for (int j = 0; j < 8; ++j) vt_s[(d0 + j) * 64 + r] = vv[j];
  }
  __syncthreads();
  const int cIdx = lane & 15, rgrp = lane >> 4;
  const f32x4 zz = {0.f, 0.f, 0.f, 0.f};
  bf16x8 qa = *(const bf16x8*)&q_s[((wave << 4) + cIdx) * 32 + (rgrp << 3)];
  f32x4 s_acc[4];
#pragma unroll
  for (int n = 0; n < 4; ++n) {
    bf16x8 kb = *(const bf16x8*)&k_s[((n << 4) + cIdx) * 32 + (rgrp << 3)];
    s_acc[n] = __builtin_amdgcn_mfma_f32_16x16x32_bf16(qa, kb, zz, 0, 0, 0);
  }
  const float scale = 0.1767766952966369f;
  float mrow[4] = {-1e30f, -1e30f, -1e30f, -1e30f};
  const float* bt = bias_tab + h * 4096 + ((wave << 4) + (rgrp << 2)) * 64 + cIdx;
#pragma unroll
  for (int n = 0; n < 4; ++n)
#pragma unroll
    for (int j = 0; j < 4; ++j) {
      float val = s_acc[n][j] * scale + bt[j * 64 + (n << 4)];
      s_acc[n][j] = val;
      mrow[j] = fmaxf(mrow[j], val);
    }
#pragma unroll
  for (int j = 0; j < 4; ++j)
#pragma unroll
    for (int o2 = 1; o2 < 16; o2 <<= 1) mrow[j] = fmaxf(mrow[j], __shfl_xor(mrow[j], o2, 64));
  float srow[4] = {0.f, 0.f, 0.f, 0.f};
#pragma unroll
  for (int n = 0; n < 4; ++n)
#pragma unroll
    for (int j = 0; j < 4; ++j) {
      float e = __expf(s_acc[n][j] - mrow[j]);
      s_acc[n][j] = e;
      srow[j] += e;
    }
#pragma unroll
  for (int j = 0; j < 4; ++j)
#pragma unroll
    for (int o2 = 1; o2 < 16; o2 <<= 1) srow[j] += __shfl_xor(srow[j], o2, 64);
  float rinv[4];
#pragma unroll
  for (int j = 0; j < 4; ++j) rinv[j] = 1.f / srow[j];
  u16* pw = p_s[wave];
#pragma unroll
  for (int n = 0; n < 4; ++n)
#pragma unroll
    for (int j = 0; j < 4; ++j)
      pw[((rgrp << 2) + j) * 72 + (n << 4) + cIdx] = f2bf(s_acc[n][j] * rinv[j]);
  f32x4 o_acc[2] = {};
#pragma unroll
  for (int kk = 0; kk < 2; ++kk) {
    bf16x8 pa = *(const bf16x8*)&pw[cIdx * 72 + (kk << 5) + (rgrp << 3)];
#pragma unroll
    for (int c2 = 0; c2 < 2; ++c2) {
      bf16x8 vb = *(const bf16x8*)&vt_s[((c2 << 4) + cIdx) * 64 + (kk << 5) + (rgrp << 3)];
      o_acc[c2] = __builtin_amdgcn_mfma_f32_16x16x32_bf16(pa, vb, o_acc[c2], 0, 0, 0);
    }
  }
#pragma unroll
  for (int c2 = 0; c2 < 2; ++c2)
#pragma unroll
    for (int j = 0; j < 4; ++j) {
      const int p = (wave << 4) + (rgrp << 2) + j;
      const int pr = p >> 3, pc = p & 7;
      const int orow = (wr0 + pr + 4) & 63, ocol = (wc0 + pc + 4) & 63;
      const size_t t = ((size_t)b << 12) + (orow << 6) + ocol;
      o[t * 384 + h * 32 + (c2 << 4) + cIdx] = f2bf(o_acc[c2][j]);
    }
}

extern "C" void kernel_launch(void* const* d_in, const int* in_sizes, int n_in,
                              void* d_out, int out_size, void* d_ws, size_t ws_size,
                              hipStream_t stream) {
  const float* x = (const float*)d_in[0];
  const float* n1g = (const float*)d_in[1];
  const float* n1b = (const float*)d_in[2];
  const float* qkv_w = (const float*)d_in[3];
  const float* qkv_b = (const float*)d_in[4];
  const float* proj_w = (const float*)d_in[5];
  const float* proj_b = (const float*)d_in[6];
  const float* rpb = (const float*)d_in[7];
  const float* n2g = (const float*)d_in[8];
  const float* n2b = (const float*)d_in[9];
  const float* fc1_w = (const float*)d_in[10];
  const float* fc1_b = (const float*)d_in[11];
  const float* fc2_w = (const float*)d_in[12];
  const float* fc2_b = (const float*)d_in[13];

  char* ws = (char*)d_ws;
  u16* wqkv = (u16*)(ws + 0);                // 442368 elems
  u16* wproj = (u16*)(ws + 884736);          // 147456
  u16* wfc1 = (u16*)(ws + 1179648);          // 589824
  u16* wfc2 = (u16*)(ws + 2359296);          // 589824
  float* bias_tab = (float*)(ws + 3538944);
  u16* qkv = (u16*)(ws + 3735552);           // region A (qkv, then m1)
  u16* m1 = qkv;
  u16* hbuf = (u16*)(ws + 205062144);        // region B (h -> o -> h2)
  u16* obuf = hbuf;
  float* x1 = (float*)d_out;

  cvt_all<<<(1769472 + 255) / 256, 256, 0, stream>>>(qkv_w, proj_w, fc1_w, fc2_w, wqkv);
  build_bias<<<192, 256, 0, stream>>>(rpb, bias_tab);

  ln_k<<<16384, 256, 0, stream>>>(x, n1g, n1b, hbuf);
  gemmA<0><<<4608, 256, 0, stream>>>(hbuf, wqkv, qkv_b, nullptr, qkv, 1152, 384, 9);
  attn_k<<<12288, 256, 0, stream>>>(qkv, bias_tab, obuf);
  gemmA<1><<<1536, 256, 0, stream>>>(obuf, wproj, proj_b, x, x1, 384, 384, 3);
  ln_k<<<16384, 256, 0, stream>>>(x1, n2g, n2b, hbuf);
  gemmA<2><<<6144, 256, 0, stream>>>(hbuf, wfc1, fc1_b, nullptr, m1, 1536, 384, 12);
  gemmA<3><<<1536, 256, 0, stream>>>(m1, wfc2, fc2_b, x1, (float*)d_out, 384, 1536, 3);
}

// Round 6
// 479.088 us; speedup vs baseline: 1.6427x; 1.0593x over previous
//
#include <hip/hip_runtime.h>
#include <hip/hip_bf16.h>
#include <math.h>

typedef __attribute__((ext_vector_type(8))) short bf16x8;
typedef __attribute__((ext_vector_type(4))) float f32x4;
typedef unsigned short u16;

#define NHEAD 12

__device__ __forceinline__ u16 f2bf(float f) {
  __hip_bfloat16 h = __float2bfloat16(f);
  return __builtin_bit_cast(u16, h);
}

__device__ __forceinline__ void gload16(const void* g, void* l) {
  __builtin_amdgcn_global_load_lds(
      (const __attribute__((address_space(1))) void*)g,
      (__attribute__((address_space(3))) void*)l, 16, 0, 0);
}

// ---------------- all weights fp32 -> bf16, packed dst ----------------
__global__ void cvt_all(const float* __restrict__ s0, const float* __restrict__ s1,
                        const float* __restrict__ s2, const float* __restrict__ s3,
                        u16* __restrict__ d) {
  int i = blockIdx.x * 256 + threadIdx.x;  // total 1769472
  if (i >= 1769472) return;
  float v;
  if (i < 442368) v = s0[i];
  else if (i < 589824) v = s1[i - 442368];
  else if (i < 1179648) v = s2[i - 589824];
  else v = s3[i - 1179648];
  d[i] = f2bf(v);
}

// ---------------- relative-position bias table [12][64][64] ----------------
__global__ void build_bias(const float* __restrict__ rpb, float* __restrict__ bt) {
  int i = blockIdx.x * 256 + threadIdx.x;
  if (i >= NHEAD * 4096) return;
  int h = i >> 12;
  int q = (i >> 6) & 63;
  int k = i & 63;
  int qi = q >> 3, qj = q & 7, ki = k >> 3, kj = k & 7;
  int idx = (qi - ki + 7) * 15 + (qj - kj + 7);
  bt[i] = rpb[idx * NHEAD + h];
}

// ---------------- LayerNorm: fp32 in -> bf16 out, C=384, 1 wave/row ----------------
__global__ __launch_bounds__(256) void ln_k(const float* __restrict__ x,
                                            const float* __restrict__ g,
                                            const float* __restrict__ b,
                                            u16* __restrict__ out) {
  int row = (blockIdx.x << 2) + (threadIdx.x >> 6);
  int lane = threadIdx.x & 63;
  const float* xr = x + (size_t)row * 384;
  float v[6];
  float s = 0.f;
#pragma unroll
  for (int i = 0; i < 6; ++i) { v[i] = xr[lane + (i << 6)]; s += v[i]; }
#pragma unroll
  for (int o = 32; o; o >>= 1) s += __shfl_xor(s, o, 64);
  float mu = s * (1.f / 384.f);
  float vs = 0.f;
#pragma unroll
  for (int i = 0; i < 6; ++i) { float d0 = v[i] - mu; vs += d0 * d0; }
#pragma unroll
  for (int o = 32; o; o >>= 1) vs += __shfl_xor(vs, o, 64);
  float rs = rsqrtf(vs * (1.f / 384.f) + 1e-5f);
  u16* orow = out + (size_t)row * 384;
#pragma unroll
  for (int i = 0; i < 6; ++i) {
    int c = lane + (i << 6);
    orow[c] = f2bf((v[i] - mu) * rs * g[c] + b[c]);
  }
}

// ---------------- m97-style GEMM ----------------
// out[M,N] = A[M,K](bf16) @ W[N,K]^T(bf16) + bias, epilogues:
// EP 0: +bias -> bf16 (QKV)   EP 1: +bias+res -> fp32 (proj)
// EP 2: +bias gelu -> bf16 (FC1)   EP 3: +bias+res -> fp32 (FC2)
// 128x128 tile, BK=64, 256 threads = 4 waves (2x2), single 32KB LDS buffer,
// 2 barriers per K-step; co-resident blocks' staggered phases hide the drain.
// XOR swizzle: row r, 16B slot s holds global col-block s^(r&7); read at
// slot (kk*4 + (lane>>4)) ^ (r&7).
template <int EP>
__global__ __launch_bounds__(256, 4) void gemmA(const u16* __restrict__ A,
                                                const u16* __restrict__ W,
                                                const float* __restrict__ bias,
                                                const float* __restrict__ res,
                                                void* __restrict__ outp,
                                                int N, int K, int nCol) {
  __shared__ u16 As[128 * 64];
  __shared__ u16 Bs[128 * 64];
  const int tid = threadIdx.x;
  const int wave = tid >> 6, lane = tid & 63;
  const int wm = wave >> 1, wn = wave & 1;
  const int nwg = gridDim.x, cpx = nwg >> 3;
  const int lin = (blockIdx.x & 7) * cpx + (blockIdx.x >> 3);
  const int rowT = lin / nCol;
  const int colT = lin - rowT * nCol;
  const int rowBase = rowT << 7;
  const int colBase = colT << 7;
  const int nK = K >> 6;

  // staging: round c covers rows c*32 + (tid>>3), slot s = tid&7; the fetched
  // global 16B col-block is s ^ (row&7) = (tid&7) ^ ((tid>>3)&7).
  const int g16 = (tid & 7) ^ ((tid >> 3) & 7);
  const u16* Asrc = A + (size_t)(rowBase + (tid >> 3)) * K + (g16 << 3);
  const u16* Wsrc = W + (size_t)(colBase + (tid >> 3)) * K + (g16 << 3);
  const int ldst = tid << 3;  // u16 idx; +c*2048 per round

  // fragment read slot: pre-slot = kk*4 + (lane>>4), XOR row&7 = lane&7
  const int q4 = lane >> 4;
  const int rx = lane & 7;
  const int arow = (wm << 6) + (lane & 15);
  const int brow = (wn << 6) + (lane & 15);

  f32x4 acc[4][4] = {};

  for (int j = 0; j < nK; ++j) {
    const size_t k0 = (size_t)j << 6;
#pragma unroll
    for (int c = 0; c < 4; ++c) {
      gload16(Asrc + (size_t)(c << 5) * K + k0, &As[(c << 11) + ldst]);
      gload16(Wsrc + (size_t)(c << 5) * K + k0, &Bs[(c << 11) + ldst]);
    }
    __syncthreads();
#pragma unroll
    for (int kk = 0; kk < 2; ++kk) {
      const int slot = (((kk << 2) + q4) ^ rx) << 3;
      bf16x8 aF[4], bF[4];
#pragma unroll
      for (int m = 0; m < 4; ++m)
        aF[m] = *(const bf16x8*)&As[(arow + (m << 4)) * 64 + slot];
#pragma unroll
      for (int n = 0; n < 4; ++n)
        bF[n] = *(const bf16x8*)&Bs[(brow + (n << 4)) * 64 + slot];
#pragma unroll
      for (int m = 0; m < 4; ++m)
#pragma unroll
        for (int n = 0; n < 4; ++n)
          acc[m][n] = __builtin_amdgcn_mfma_f32_16x16x32_bf16(aF[m], bF[n], acc[m][n], 0, 0, 0);
    }
    __syncthreads();
  }

#pragma unroll
  for (int m = 0; m < 4; ++m) {
#pragma unroll
    for (int n = 0; n < 4; ++n) {
      const int col = colBase + (wn << 6) + (n << 4) + (lane & 15);
      const int row0 = rowBase + (wm << 6) + (m << 4) + ((lane >> 4) << 2);
      const float bv = bias[col];
#pragma unroll
      for (int jj = 0; jj < 4; ++jj) {
        const size_t row = (size_t)(row0 + jj);
        float y = acc[m][n][jj] + bv;
        if (EP == 0) {
          ((u16*)outp)[row * N + col] = f2bf(y);
        } else if (EP == 1) {
          ((float*)outp)[row * N + col] = y + res[row * N + col];
        } else if (EP == 2) {
          // gelu = y * sigmoid(2u); exact algebraic rewrite of the tanh form.
          // exp2 constants: c1 = 2*0.7978845608*log2(e), c2 = c1*0.044715
          float y2 = y * y;
          float t = __builtin_fmaf(y2, 0.1029434f, 2.3022118f);
          float e = __builtin_amdgcn_exp2f(-(y * t));
          y = y * __builtin_amdgcn_rcpf(1.f + e);
          ((u16*)outp)[row * N + col] = f2bf(y);
        } else {
          ((float*)outp)[row * N + col] = y + res[row * N + col];
        }
      }
    }
  }
}

// ---------------- window attention: one block per (window, head) ----------------
// XCD swizzle: 12 consecutive logical ids (= the 12 heads of one window) land
// in one XCD chunk so they share the window's qkv rows in that XCD's L2.
__global__ __launch_bounds__(256) void attn_k(const u16* __restrict__ qkv,
                                              const float* __restrict__ bias_tab,
                                              u16* __restrict__ o) {
  const int cpx = gridDim.x >> 3;
  const int lin = (blockIdx.x & 7) * cpx + (blockIdx.x >> 3);
  const int w = lin / NHEAD;
  const int h = lin - w * NHEAD;
  const int tid = threadIdx.x, wave = tid >> 6, lane = tid & 63;
  __shared__ u16 q_s[64 * 32];
  __shared__ u16 k_s[64 * 32];
  __shared__ u16 vt_s[32 * 64];
  __shared__ u16 p_s[4][16 * 72];
  const int b = w >> 6;
  const int wim = w & 63;
  const int wr0 = (wim >> 3) << 3, wc0 = (wim & 7) << 3;
  {
    const int r = tid >> 2, d0 = (tid & 3) << 3;
    const int pr = r >> 3, pc = r & 7;
    const int orow = (wr0 + pr + 4) & 63, ocol = (wc0 + pc + 4) & 63;
    const size_t t = ((size_t)b << 12) + (orow << 6) + ocol;
    const u16* base = qkv + t * 1152 + h * 32 + d0;
    *(uint4*)&q_s[r * 32 + d0] = *(const uint4*)(base);
    *(uint4*)&k_s[r * 32 + d0] = *(const uint4*)(base + 384);
    u16 vv[8];
    *(uint4*)vv = *(const uint4*)(base + 768);
#pragma unroll
    for (int j = 0; j < 8; ++j) vt_s[(d0 + j) * 64 + r] = vv[j];
  }
  __syncthreads();
  const int cIdx = lane & 15, rgrp = lane >> 4;
  const f32x4 zz = {0.f, 0.f, 0.f, 0.f};
  bf16x8 qa = *(const bf16x8*)&q_s[((wave << 4) + cIdx) * 32 + (rgrp << 3)];
  f32x4 s_acc[4];
#pragma unroll
  for (int n = 0; n < 4; ++n) {
    bf16x8 kb = *(const bf16x8*)&k_s[((n << 4) + cIdx) * 32 + (rgrp << 3)];
    s_acc[n] = __builtin_amdgcn_mfma_f32_16x16x32_bf16(qa, kb, zz, 0, 0, 0);
  }
  const float scale = 0.1767766952966369f;
  float mrow[4] = {-1e30f, -1e30f, -1e30f, -1e30f};
  const float* bt = bias_tab + h * 4096 + ((wave << 4) + (rgrp << 2)) * 64 + cIdx;
#pragma unroll
  for (int n = 0; n < 4; ++n)
#pragma unroll
    for (int j = 0; j < 4; ++j) {
      float val = s_acc[n][j] * scale + bt[j * 64 + (n << 4)];
      s_acc[n][j] = val;
      mrow[j] = fmaxf(mrow[j], val);
    }
#pragma unroll
  for (int j = 0; j < 4; ++j)
#pragma unroll
    for (int o2 = 1; o2 < 16; o2 <<= 1) mrow[j] = fmaxf(mrow[j], __shfl_xor(mrow[j], o2, 64));
  float srow[4] = {0.f, 0.f, 0.f, 0.f};
#pragma unroll
  for (int n = 0; n < 4; ++n)
#pragma unroll
    for (int j = 0; j < 4; ++j) {
      float e = __expf(s_acc[n][j] - mrow[j]);
      s_acc[n][j] = e;
      srow[j] += e;
    }
#pragma unroll
  for (int j = 0; j < 4; ++j)
#pragma unroll
    for (int o2 = 1; o2 < 16; o2 <<= 1) srow[j] += __shfl_xor(srow[j], o2, 64);
  float rinv[4];
#pragma unroll
  for (int j = 0; j < 4; ++j) rinv[j] = 1.f / srow[j];
  u16* pw = p_s[wave];
#pragma unroll
  for (int n = 0; n < 4; ++n)
#pragma unroll
    for (int j = 0; j < 4; ++j)
      pw[((rgrp << 2) + j) * 72 + (n << 4) + cIdx] = f2bf(s_acc[n][j] * rinv[j]);
  f32x4 o_acc[2] = {};
#pragma unroll
  for (int kk = 0; kk < 2; ++kk) {
    bf16x8 pa = *(const bf16x8*)&pw[cIdx * 72 + (kk << 5) + (rgrp << 3)];
#pragma unroll
    for (int c2 = 0; c2 < 2; ++c2) {
      bf16x8 vb = *(const bf16x8*)&vt_s[((c2 << 4) + cIdx) * 64 + (kk << 5) + (rgrp << 3)];
      o_acc[c2] = __builtin_amdgcn_mfma_f32_16x16x32_bf16(pa, vb, o_acc[c2], 0, 0, 0);
    }
  }
#pragma unroll
  for (int c2 = 0; c2 < 2; ++c2)
#pragma unroll
    for (int j = 0; j < 4; ++j) {
      const int p = (wave << 4) + (rgrp << 2) + j;
      const int pr = p >> 3, pc = p & 7;
      const int orow = (wr0 + pr + 4) & 63, ocol = (wc0 + pc + 4) & 63;
      const size_t t = ((size_t)b << 12) + (orow << 6) + ocol;
      o[t * 384 + h * 32 + (c2 << 4) + cIdx] = f2bf(o_acc[c2][j]);
    }
}

extern "C" void kernel_launch(void* const* d_in, const int* in_sizes, int n_in,
                              void* d_out, int out_size, void* d_ws, size_t ws_size,
                              hipStream_t stream) {
  const float* x = (const float*)d_in[0];
  const float* n1g = (const float*)d_in[1];
  const float* n1b = (const float*)d_in[2];
  const float* qkv_w = (const float*)d_in[3];
  const float* qkv_b = (const float*)d_in[4];
  const float* proj_w = (const float*)d_in[5];
  const float* proj_b = (const float*)d_in[6];
  const float* rpb = (const float*)d_in[7];
  const float* n2g = (const float*)d_in[8];
  const float* n2b = (const float*)d_in[9];
  const float* fc1_w = (const float*)d_in[10];
  const float* fc1_b = (const float*)d_in[11];
  const float* fc2_w = (const float*)d_in[12];
  const float* fc2_b = (const float*)d_in[13];

  char* ws = (char*)d_ws;
  u16* wqkv = (u16*)(ws + 0);                // 442368 elems
  u16* wproj = (u16*)(ws + 884736);          // 147456
  u16* wfc1 = (u16*)(ws + 1179648);          // 589824
  u16* wfc2 = (u16*)(ws + 2359296);          // 589824
  float* bias_tab = (float*)(ws + 3538944);
  u16* qkv = (u16*)(ws + 3735552);           // region A (qkv, then m1)
  u16* m1 = qkv;
  u16* hbuf = (u16*)(ws + 205062144);        // region B (h -> o -> h2)
  u16* obuf = hbuf;
  float* x1 = (float*)d_out;

  cvt_all<<<(1769472 + 255) / 256, 256, 0, stream>>>(qkv_w, proj_w, fc1_w, fc2_w, wqkv);
  build_bias<<<192, 256, 0, stream>>>(rpb, bias_tab);

  ln_k<<<16384, 256, 0, stream>>>(x, n1g, n1b, hbuf);
  gemmA<0><<<4608, 256, 0, stream>>>(hbuf, wqkv, qkv_b, nullptr, qkv, 1152, 384, 9);
  attn_k<<<12288, 256, 0, stream>>>(qkv, bias_tab, obuf);
  gemmA<1><<<1536, 256, 0, stream>>>(obuf, wproj, proj_b, x, x1, 384, 384, 3);
  ln_k<<<16384, 256, 0, stream>>>(x1, n2g, n2b, hbuf);
  gemmA<2><<<6144, 256, 0, stream>>>(hbuf, wfc1, fc1_b, nullptr, m1, 1536, 384, 12);
  gemmA<3><<<1536, 256, 0, stream>>>(m1, wfc2, fc2_b, x1, (float*)d_out, 384, 1536, 3);
}